// Round 1
// baseline (2233.140 us; speedup 1.0000x reference)
//
#include <hip/hip_runtime.h>

#define N_NODES 100000
#define N_EDGES 500000
#define NODE_IN 16
#define HID 128

__device__ __forceinline__ float elu_f(float v) {
    return v > 0.f ? v : __expf(v) - 1.f;
}

// ---------------------------------------------------------------------------
// Layer 0 message+scatter: m = relu(x[src] + ea*We0 + be0)  -> atomicAdd aggr[dst]
// one thread per (edge, feature), NODE_IN=16
// ---------------------------------------------------------------------------
__global__ __launch_bounds__(256) void scatter0_kernel(
    const float* __restrict__ x, const int* __restrict__ ei,
    const float* __restrict__ ea, const float* __restrict__ We0,
    const float* __restrict__ be0, float* __restrict__ aggr)
{
    int idx = blockIdx.x * 256 + threadIdx.x;   // E*16 = 8M, fits int
    int e = idx >> 4, c = idx & 15;
    int s = ei[e], d = ei[N_EDGES + e];
    float m = x[s * NODE_IN + c] + ea[e] * We0[c] + be0[c];
    m = fmaxf(m, 0.f);
    atomicAdd(&aggr[d * NODE_IN + c], m);
}

// ---------------------------------------------------------------------------
// HID-layer message+scatter: m = relu(h[src] + ea*We + be) -> atomicAdd aggr[dst]
// one thread per (edge, feature), HID=128
// ---------------------------------------------------------------------------
__global__ __launch_bounds__(256) void scatterH_kernel(
    const float* __restrict__ h, const int* __restrict__ ei,
    const float* __restrict__ ea, const float* __restrict__ We,
    const float* __restrict__ be, float* __restrict__ aggr)
{
    int idx = blockIdx.x * 256 + threadIdx.x;   // E*128 = 64M, fits int
    int e = idx >> 7, c = idx & 127;
    int s = ei[e], d = ei[N_EDGES + e];
    float m = h[s * HID + c] + ea[e] * We[c] + be[c];
    m = fmaxf(m, 0.f);
    atomicAdd(&aggr[d * HID + c], m);
}

// ---------------------------------------------------------------------------
// Layer 0 MLP: h = elu( elu((x+aggr0) @ W1[16,128] + b1) @ W2[128,128] + b2 )
// 32 rows per block, 256 threads: thread = (col c, half); each owns 16 rows.
// ---------------------------------------------------------------------------
__global__ __launch_bounds__(256) void mlp0_kernel(
    const float* __restrict__ x, const float* __restrict__ aggr,
    const float* __restrict__ W1, const float* __restrict__ b1,
    const float* __restrict__ W2, const float* __restrict__ b2,
    float* __restrict__ h)
{
    __shared__ float in0[32][NODE_IN];
    __shared__ float mid[32][HID];
    const int t = threadIdx.x;
    const int base = blockIdx.x * 32;           // 100000/32 = 3125 exact

    for (int i = t; i < 32 * NODE_IN; i += 256) {
        int r = i >> 4, cc = i & 15;
        int n = base + r;
        in0[r][cc] = x[n * NODE_IN + cc] + aggr[n * NODE_IN + cc];
    }
    __syncthreads();

    const int c = t & 127, half = t >> 7;
    float acc[16];
#pragma unroll
    for (int i = 0; i < 16; i++) acc[i] = b1[c];
    for (int k = 0; k < NODE_IN; k += 4) {
        float w0 = W1[(k + 0) * HID + c], w1 = W1[(k + 1) * HID + c];
        float w2 = W1[(k + 2) * HID + c], w3 = W1[(k + 3) * HID + c];
#pragma unroll
        for (int i = 0; i < 16; i++) {
            float4 v = *(const float4*)&in0[half * 16 + i][k];
            acc[i] = fmaf(v.x, w0, fmaf(v.y, w1, fmaf(v.z, w2, fmaf(v.w, w3, acc[i]))));
        }
    }
#pragma unroll
    for (int i = 0; i < 16; i++) mid[half * 16 + i][c] = elu_f(acc[i]);
    __syncthreads();

    float acc2[16];
#pragma unroll
    for (int i = 0; i < 16; i++) acc2[i] = b2[c];
    for (int k = 0; k < HID; k += 4) {
        float w0 = W2[(k + 0) * HID + c], w1 = W2[(k + 1) * HID + c];
        float w2 = W2[(k + 2) * HID + c], w3 = W2[(k + 3) * HID + c];
#pragma unroll
        for (int i = 0; i < 16; i++) {
            float4 v = *(const float4*)&mid[half * 16 + i][k];
            acc2[i] = fmaf(v.x, w0, fmaf(v.y, w1, fmaf(v.z, w2, fmaf(v.w, w3, acc2[i]))));
        }
    }
#pragma unroll
    for (int i = 0; i < 16; i++)
        h[(base + half * 16 + i) * HID + c] = elu_f(acc2[i]);
}

// ---------------------------------------------------------------------------
// HID-layer MLP: h = elu( elu((h+aggr) @ W1 + b1) @ W2 + b2 )   (in-place safe:
// each block reads only its own 32 rows before writing them)
// ---------------------------------------------------------------------------
__global__ __launch_bounds__(256) void mlpH_kernel(
    const float* __restrict__ hin, const float* __restrict__ aggr,
    const float* __restrict__ W1, const float* __restrict__ b1,
    const float* __restrict__ W2, const float* __restrict__ b2,
    float* __restrict__ hout)
{
    __shared__ float in[32][HID];
    __shared__ float mid[32][HID];
    const int t = threadIdx.x;
    const int base = blockIdx.x * 32;

    for (int i = t; i < 32 * HID; i += 256) {
        int r = i >> 7, cc = i & 127;
        int n = base + r;
        in[r][cc] = hin[n * HID + cc] + aggr[n * HID + cc];
    }
    __syncthreads();

    const int c = t & 127, half = t >> 7;
    float acc[16];
#pragma unroll
    for (int i = 0; i < 16; i++) acc[i] = b1[c];
    for (int k = 0; k < HID; k += 4) {
        float w0 = W1[(k + 0) * HID + c], w1 = W1[(k + 1) * HID + c];
        float w2 = W1[(k + 2) * HID + c], w3 = W1[(k + 3) * HID + c];
#pragma unroll
        for (int i = 0; i < 16; i++) {
            float4 v = *(const float4*)&in[half * 16 + i][k];
            acc[i] = fmaf(v.x, w0, fmaf(v.y, w1, fmaf(v.z, w2, fmaf(v.w, w3, acc[i]))));
        }
    }
#pragma unroll
    for (int i = 0; i < 16; i++) mid[half * 16 + i][c] = elu_f(acc[i]);
    __syncthreads();

    float acc2[16];
#pragma unroll
    for (int i = 0; i < 16; i++) acc2[i] = b2[c];
    for (int k = 0; k < HID; k += 4) {
        float w0 = W2[(k + 0) * HID + c], w1 = W2[(k + 1) * HID + c];
        float w2 = W2[(k + 2) * HID + c], w3 = W2[(k + 3) * HID + c];
#pragma unroll
        for (int i = 0; i < 16; i++) {
            float4 v = *(const float4*)&mid[half * 16 + i][k];
            acc2[i] = fmaf(v.x, w0, fmaf(v.y, w1, fmaf(v.z, w2, fmaf(v.w, w3, acc2[i]))));
        }
    }
#pragma unroll
    for (int i = 0; i < 16; i++)
        hout[(base + half * 16 + i) * HID + c] = elu_f(acc2[i]);
}

// ---------------------------------------------------------------------------
// Edge predictor: out[e] = elu([h[src]|h[dst]] @ Wp1 + bp1) @ Wp2 + bp2
// 32 edges per block.
// ---------------------------------------------------------------------------
__global__ __launch_bounds__(256) void pred_kernel(
    const float* __restrict__ h, const int* __restrict__ ei,
    const float* __restrict__ Wp1, const float* __restrict__ bp1,
    const float* __restrict__ Wp2, const float* __restrict__ bp2,
    float* __restrict__ out)
{
    __shared__ float f[32][2 * HID];
    __shared__ float mid[32][HID];
    const int t = threadIdx.x;
    const int ebase = blockIdx.x * 32;          // 500000/32 = 15625 exact

    for (int i = t; i < 32 * 2 * HID; i += 256) {
        int r = i >> 8, cc = i & 255;
        int e = ebase + r;
        int node = (cc < HID) ? ei[e] : ei[N_EDGES + e];
        f[r][cc] = h[node * HID + (cc & 127)];
    }
    __syncthreads();

    const int c = t & 127, half = t >> 7;
    float acc[16];
#pragma unroll
    for (int i = 0; i < 16; i++) acc[i] = bp1[c];
    for (int k = 0; k < 2 * HID; k += 4) {
        float w0 = Wp1[(k + 0) * HID + c], w1 = Wp1[(k + 1) * HID + c];
        float w2 = Wp1[(k + 2) * HID + c], w3 = Wp1[(k + 3) * HID + c];
#pragma unroll
        for (int i = 0; i < 16; i++) {
            float4 v = *(const float4*)&f[half * 16 + i][k];
            acc[i] = fmaf(v.x, w0, fmaf(v.y, w1, fmaf(v.z, w2, fmaf(v.w, w3, acc[i]))));
        }
    }
#pragma unroll
    for (int i = 0; i < 16; i++) mid[half * 16 + i][c] = elu_f(acc[i]);
    __syncthreads();

    // second GEMM is 128 -> 1: 8 threads per edge, shuffle-reduce
    const int e = t >> 3, j = t & 7;
    float s = 0.f;
#pragma unroll
    for (int m = 0; m < 16; m++) {
        int cc = j * 16 + m;
        s = fmaf(mid[e][cc], Wp2[cc], s);
    }
    s += __shfl_down(s, 4, 8);
    s += __shfl_down(s, 2, 8);
    s += __shfl_down(s, 1, 8);
    if (j == 0) out[ebase + e] = s + bp2[0];
}

// ---------------------------------------------------------------------------
extern "C" void kernel_launch(void* const* d_in, const int* in_sizes, int n_in,
                              void* d_out, int out_size, void* d_ws, size_t ws_size,
                              hipStream_t stream) {
    const float* x    = (const float*)d_in[0];
    const int*   ei   = (const int*)d_in[1];
    const float* ea   = (const float*)d_in[2];
    const float* We0  = (const float*)d_in[3];
    const float* be0  = (const float*)d_in[4];
    const float* W10  = (const float*)d_in[5];
    const float* b10  = (const float*)d_in[6];
    const float* W20  = (const float*)d_in[7];
    const float* b20  = (const float*)d_in[8];
    const float* We_s = (const float*)d_in[9];
    const float* be_s = (const float*)d_in[10];
    const float* W1_s = (const float*)d_in[11];
    const float* b1_s = (const float*)d_in[12];
    const float* W2_s = (const float*)d_in[13];
    const float* b2_s = (const float*)d_in[14];
    const float* Wp1  = (const float*)d_in[15];
    const float* bp1  = (const float*)d_in[16];
    const float* Wp2  = (const float*)d_in[17];
    const float* bp2  = (const float*)d_in[18];
    float* out = (float*)d_out;

    float* h    = (float*)d_ws;                       // N*128 f32 = 51.2 MB
    float* aggr = h + (size_t)N_NODES * HID;          // N*128 f32 = 51.2 MB

    // ----- layer 0 (NODE_IN -> HID) -----
    hipMemsetAsync(aggr, 0, (size_t)N_NODES * NODE_IN * sizeof(float), stream);
    scatter0_kernel<<<(N_EDGES * NODE_IN) / 256, 256, 0, stream>>>(x, ei, ea, We0, be0, aggr);
    mlp0_kernel<<<N_NODES / 32, 256, 0, stream>>>(x, aggr, W10, b10, W20, b20, h);

    // ----- layers 1..4 (HID -> HID) -----
    for (int l = 0; l < 4; l++) {
        hipMemsetAsync(aggr, 0, (size_t)N_NODES * HID * sizeof(float), stream);
        scatterH_kernel<<<(N_EDGES * HID) / 256, 256, 0, stream>>>(
            h, ei, ea, We_s + l * HID, be_s + l * HID, aggr);
        mlpH_kernel<<<N_NODES / 32, 256, 0, stream>>>(
            h, aggr, W1_s + (size_t)l * HID * HID, b1_s + l * HID,
            W2_s + (size_t)l * HID * HID, b2_s + l * HID, h);
    }

    // ----- edge predictor -----
    pred_kernel<<<N_EDGES / 32, 256, 0, stream>>>(h, ei, Wp1, bp1, Wp2, bp2, out);
}

// Round 2
// 1493.727 us; speedup vs baseline: 1.4950x; 1.4950x over previous
//
#include <hip/hip_runtime.h>

#define N_NODES 100000
#define N_EDGES 500000
#define NODE_IN 16
#define HID 128
#define INP 132           // padded LDS row stride (floats): 132%32=4 -> no bank aliasing
#define PIN 260           // padded stride for 2*HID
#define SCAN_CHUNK 1024
#define NB_SCAN ((N_NODES + SCAN_CHUNK - 1) / SCAN_CHUNK)   // 98

__device__ __forceinline__ float elu_f(float v) {
    return v > 0.f ? v : __expf(v) - 1.f;
}

// ===========================================================================
// CSR-by-dst build: deg -> rowPtr (3-phase scan) -> cursor -> edge_of
// ===========================================================================
__global__ void deg_count_kernel(const int* __restrict__ ei, int* __restrict__ deg) {
    int e = blockIdx.x * 256 + threadIdx.x;
    if (e < N_EDGES) atomicAdd(&deg[ei[N_EDGES + e]], 1);
}

__global__ __launch_bounds__(1024) void scanA_kernel(const int* __restrict__ deg, int* __restrict__ bsum) {
    __shared__ int s[SCAN_CHUNK];
    int i = blockIdx.x * SCAN_CHUNK + threadIdx.x;
    s[threadIdx.x] = (i < N_NODES) ? deg[i] : 0;
    __syncthreads();
    for (int off = SCAN_CHUNK / 2; off > 0; off >>= 1) {
        if (threadIdx.x < off) s[threadIdx.x] += s[threadIdx.x + off];
        __syncthreads();
    }
    if (threadIdx.x == 0) bsum[blockIdx.x] = s[0];
}

__global__ void scanB_kernel(const int* __restrict__ bsum, int* __restrict__ boff) {
    if (threadIdx.x == 0 && blockIdx.x == 0) {
        int r = 0;
        for (int i = 0; i < NB_SCAN; i++) { boff[i] = r; r += bsum[i]; }
    }
}

__global__ __launch_bounds__(1024) void scanC_kernel(const int* __restrict__ deg,
                                                     const int* __restrict__ boff,
                                                     int* __restrict__ rowPtr,
                                                     int* __restrict__ cursor) {
    __shared__ int bufA[SCAN_CHUNK], bufB[SCAN_CHUNK];
    int i = blockIdx.x * SCAN_CHUNK + threadIdx.x;
    int t = threadIdx.x;
    bufA[t] = (i < N_NODES) ? deg[i] : 0;
    __syncthreads();
    int* src = bufA; int* dst = bufB;
    for (int off = 1; off < SCAN_CHUNK; off <<= 1) {
        dst[t] = (t >= off) ? (src[t - off] + src[t]) : src[t];
        __syncthreads();
        int* tmp = src; src = dst; dst = tmp;
    }
    if (i < N_NODES) {
        int excl = (t == 0) ? 0 : src[t - 1];
        int v = excl + boff[blockIdx.x];
        rowPtr[i] = v;
        cursor[i] = v;
    }
}

__global__ void fill_kernel(const int* __restrict__ ei, int* __restrict__ cursor,
                            int* __restrict__ edge_of) {
    int e = blockIdx.x * 256 + threadIdx.x;
    if (e < N_EDGES) {
        int d = ei[N_EDGES + e];
        int p = atomicAdd(&cursor[d], 1);
        edge_of[p] = e;
    }
}

// ===========================================================================
// Layer 0 scatter (NODE_IN=16, cheap: 8M atomics)
// ===========================================================================
__global__ __launch_bounds__(256) void scatter0_kernel(
    const float* __restrict__ x, const int* __restrict__ ei,
    const float* __restrict__ ea, const float* __restrict__ We0,
    const float* __restrict__ be0, float* __restrict__ aggr)
{
    int idx = blockIdx.x * 256 + threadIdx.x;
    int e = idx >> 4, c = idx & 15;
    int s = ei[e], d = ei[N_EDGES + e];
    float m = x[s * NODE_IN + c] + ea[e] * We0[c] + be0[c];
    m = fmaxf(m, 0.f);
    atomicAdd(&aggr[d * NODE_IN + c], m);
}

// ---------------------------------------------------------------------------
// 4x4 register-blocked FMA helper: acc[i][c] += r[i][k] * w[k][c]
// ---------------------------------------------------------------------------
__device__ __forceinline__ void fma4x4(float (&acc)[4][4],
    const float4& r0, const float4& r1, const float4& r2, const float4& r3,
    const float4& w0, const float4& w1, const float4& w2, const float4& w3)
{
    float r[4][4] = {{r0.x, r0.y, r0.z, r0.w}, {r1.x, r1.y, r1.z, r1.w},
                     {r2.x, r2.y, r2.z, r2.w}, {r3.x, r3.y, r3.z, r3.w}};
    float w[4][4] = {{w0.x, w0.y, w0.z, w0.w}, {w1.x, w1.y, w1.z, w1.w},
                     {w2.x, w2.y, w2.z, w2.w}, {w3.x, w3.y, w3.z, w3.w}};
#pragma unroll
    for (int i = 0; i < 4; i++)
#pragma unroll
        for (int k = 0; k < 4; k++)
#pragma unroll
            for (int c = 0; c < 4; c++)
                acc[i][c] = fmaf(r[i][k], w[k][c], acc[i][c]);
}

// ===========================================================================
// Layer 0 MLP: h = elu( elu((x+aggr0) @ W1[16,128] + b1) @ W2[128,128] + b2 )
// thread = (q = t&31 -> cols 4q..4q+3, g = t>>5 -> rows 4g..4g+3)
// ===========================================================================
__global__ __launch_bounds__(256) void mlp0_kernel(
    const float* __restrict__ x, const float* __restrict__ aggr,
    const float* __restrict__ W1, const float* __restrict__ b1,
    const float* __restrict__ W2, const float* __restrict__ b2,
    float* __restrict__ h)
{
    __shared__ float in0[32][20];       // stride 20 floats = 80B, 16B-aligned rows
    __shared__ float mid[32][INP];
    const int t = threadIdx.x;
    const int q = t & 31, g = t >> 5;
    const int c0 = q * 4;
    const int base = blockIdx.x * 32;

    for (int i = t; i < 32 * NODE_IN; i += 256) {
        int r = i >> 4, cc = i & 15;
        int n = base + r;
        in0[r][cc] = x[n * NODE_IN + cc] + aggr[n * NODE_IN + cc];
    }
    __syncthreads();

    float4 bb = *(const float4*)&b1[c0];
    float acc[4][4];
#pragma unroll
    for (int i = 0; i < 4; i++) { acc[i][0] = bb.x; acc[i][1] = bb.y; acc[i][2] = bb.z; acc[i][3] = bb.w; }
    for (int k = 0; k < NODE_IN; k += 4) {
        float4 r0 = *(const float4*)&in0[g * 4 + 0][k];
        float4 r1 = *(const float4*)&in0[g * 4 + 1][k];
        float4 r2 = *(const float4*)&in0[g * 4 + 2][k];
        float4 r3 = *(const float4*)&in0[g * 4 + 3][k];
        float4 w0 = *(const float4*)&W1[(k + 0) * HID + c0];
        float4 w1 = *(const float4*)&W1[(k + 1) * HID + c0];
        float4 w2 = *(const float4*)&W1[(k + 2) * HID + c0];
        float4 w3 = *(const float4*)&W1[(k + 3) * HID + c0];
        fma4x4(acc, r0, r1, r2, r3, w0, w1, w2, w3);
    }
#pragma unroll
    for (int i = 0; i < 4; i++)
        *(float4*)&mid[g * 4 + i][c0] = make_float4(elu_f(acc[i][0]), elu_f(acc[i][1]),
                                                    elu_f(acc[i][2]), elu_f(acc[i][3]));
    __syncthreads();

    float4 bb2 = *(const float4*)&b2[c0];
    float acc2[4][4];
#pragma unroll
    for (int i = 0; i < 4; i++) { acc2[i][0] = bb2.x; acc2[i][1] = bb2.y; acc2[i][2] = bb2.z; acc2[i][3] = bb2.w; }
    for (int k = 0; k < HID; k += 4) {
        float4 r0 = *(const float4*)&mid[g * 4 + 0][k];
        float4 r1 = *(const float4*)&mid[g * 4 + 1][k];
        float4 r2 = *(const float4*)&mid[g * 4 + 2][k];
        float4 r3 = *(const float4*)&mid[g * 4 + 3][k];
        float4 w0 = *(const float4*)&W2[(k + 0) * HID + c0];
        float4 w1 = *(const float4*)&W2[(k + 1) * HID + c0];
        float4 w2 = *(const float4*)&W2[(k + 2) * HID + c0];
        float4 w3 = *(const float4*)&W2[(k + 3) * HID + c0];
        fma4x4(acc2, r0, r1, r2, r3, w0, w1, w2, w3);
    }
#pragma unroll
    for (int i = 0; i < 4; i++)
        *(float4*)&h[(base + g * 4 + i) * HID + c0] = make_float4(
            elu_f(acc2[i][0]), elu_f(acc2[i][1]), elu_f(acc2[i][2]), elu_f(acc2[i][3]));
}

// ===========================================================================
// Fused GINE HID layer: gather+aggregate (CSR) + Linear-ELU-Linear + outer ELU
// hin -> hout (double-buffered; blocks read neighbor rows of hin only)
// ===========================================================================
__global__ __launch_bounds__(256) void gine_fused_kernel(
    const float* __restrict__ hin, const int* __restrict__ ei,
    const float* __restrict__ ea, const int* __restrict__ rowPtr,
    const int* __restrict__ deg, const int* __restrict__ edge_of,
    const float* __restrict__ We, const float* __restrict__ be,
    const float* __restrict__ W1, const float* __restrict__ b1,
    const float* __restrict__ W2, const float* __restrict__ b2,
    float* __restrict__ hout)
{
    __shared__ float in[32][INP];
    __shared__ float mid[32][INP];
    const int t = threadIdx.x;
    const int q = t & 31, g = t >> 5;
    const int c0 = q * 4;
    const int base = blockIdx.x * 32;

    // stage 1: in[r] = hin[n] + sum_{e in in(n)} relu(hin[src_e] + ea_e*We + be)
    float4 wev = *(const float4*)&We[c0];
    float4 bev = *(const float4*)&be[c0];
#pragma unroll
    for (int i = 0; i < 4; i++) {
        int r = g * 4 + i, n = base + r;
        float4 acc = *(const float4*)&hin[n * HID + c0];
        int s0 = rowPtr[n], d = deg[n];
        for (int j = 0; j < d; j++) {
            int eid = edge_of[s0 + j];
            int s = ei[eid];
            float av = ea[eid];
            float4 hv = *(const float4*)&hin[s * HID + c0];
            acc.x += fmaxf(fmaf(av, wev.x, bev.x) + hv.x, 0.f);
            acc.y += fmaxf(fmaf(av, wev.y, bev.y) + hv.y, 0.f);
            acc.z += fmaxf(fmaf(av, wev.z, bev.z) + hv.z, 0.f);
            acc.w += fmaxf(fmaf(av, wev.w, bev.w) + hv.w, 0.f);
        }
        *(float4*)&in[r][c0] = acc;
    }
    __syncthreads();

    // stage 2: mid = elu(in @ W1 + b1)
    float4 bb = *(const float4*)&b1[c0];
    float acc[4][4];
#pragma unroll
    for (int i = 0; i < 4; i++) { acc[i][0] = bb.x; acc[i][1] = bb.y; acc[i][2] = bb.z; acc[i][3] = bb.w; }
    for (int k = 0; k < HID; k += 4) {
        float4 r0 = *(const float4*)&in[g * 4 + 0][k];
        float4 r1 = *(const float4*)&in[g * 4 + 1][k];
        float4 r2 = *(const float4*)&in[g * 4 + 2][k];
        float4 r3 = *(const float4*)&in[g * 4 + 3][k];
        float4 w0 = *(const float4*)&W1[(k + 0) * HID + c0];
        float4 w1 = *(const float4*)&W1[(k + 1) * HID + c0];
        float4 w2 = *(const float4*)&W1[(k + 2) * HID + c0];
        float4 w3 = *(const float4*)&W1[(k + 3) * HID + c0];
        fma4x4(acc, r0, r1, r2, r3, w0, w1, w2, w3);
    }
#pragma unroll
    for (int i = 0; i < 4; i++)
        *(float4*)&mid[g * 4 + i][c0] = make_float4(elu_f(acc[i][0]), elu_f(acc[i][1]),
                                                    elu_f(acc[i][2]), elu_f(acc[i][3]));
    __syncthreads();

    // stage 3: hout = elu(mid @ W2 + b2)
    float4 bb2 = *(const float4*)&b2[c0];
    float acc2[4][4];
#pragma unroll
    for (int i = 0; i < 4; i++) { acc2[i][0] = bb2.x; acc2[i][1] = bb2.y; acc2[i][2] = bb2.z; acc2[i][3] = bb2.w; }
    for (int k = 0; k < HID; k += 4) {
        float4 r0 = *(const float4*)&mid[g * 4 + 0][k];
        float4 r1 = *(const float4*)&mid[g * 4 + 1][k];
        float4 r2 = *(const float4*)&mid[g * 4 + 2][k];
        float4 r3 = *(const float4*)&mid[g * 4 + 3][k];
        float4 w0 = *(const float4*)&W2[(k + 0) * HID + c0];
        float4 w1 = *(const float4*)&W2[(k + 1) * HID + c0];
        float4 w2 = *(const float4*)&W2[(k + 2) * HID + c0];
        float4 w3 = *(const float4*)&W2[(k + 3) * HID + c0];
        fma4x4(acc2, r0, r1, r2, r3, w0, w1, w2, w3);
    }
#pragma unroll
    for (int i = 0; i < 4; i++)
        *(float4*)&hout[(base + g * 4 + i) * HID + c0] = make_float4(
            elu_f(acc2[i][0]), elu_f(acc2[i][1]), elu_f(acc2[i][2]), elu_f(acc2[i][3]));
}

// ===========================================================================
// Edge predictor: out[e] = elu([h[src]|h[dst]] @ Wp1 + bp1) @ Wp2 + bp2
// ===========================================================================
__global__ __launch_bounds__(256) void pred_kernel(
    const float* __restrict__ h, const int* __restrict__ ei,
    const float* __restrict__ Wp1, const float* __restrict__ bp1,
    const float* __restrict__ Wp2, const float* __restrict__ bp2,
    float* __restrict__ out)
{
    __shared__ float f[32][PIN];
    __shared__ float mid[32][INP];
    const int t = threadIdx.x;
    const int q = t & 31, g = t >> 5;
    const int c0 = q * 4;
    const int ebase = blockIdx.x * 32;

#pragma unroll
    for (int i = 0; i < 4; i++) {
        int r = g * 4 + i, e = ebase + r;
        int s = ei[e], d = ei[N_EDGES + e];
        *(float4*)&f[r][c0]       = *(const float4*)&h[s * HID + c0];
        *(float4*)&f[r][HID + c0] = *(const float4*)&h[d * HID + c0];
    }
    __syncthreads();

    float4 bb = *(const float4*)&bp1[c0];
    float acc[4][4];
#pragma unroll
    for (int i = 0; i < 4; i++) { acc[i][0] = bb.x; acc[i][1] = bb.y; acc[i][2] = bb.z; acc[i][3] = bb.w; }
    for (int k = 0; k < 2 * HID; k += 4) {
        float4 r0 = *(const float4*)&f[g * 4 + 0][k];
        float4 r1 = *(const float4*)&f[g * 4 + 1][k];
        float4 r2 = *(const float4*)&f[g * 4 + 2][k];
        float4 r3 = *(const float4*)&f[g * 4 + 3][k];
        float4 w0 = *(const float4*)&Wp1[(k + 0) * HID + c0];
        float4 w1 = *(const float4*)&Wp1[(k + 1) * HID + c0];
        float4 w2 = *(const float4*)&Wp1[(k + 2) * HID + c0];
        float4 w3 = *(const float4*)&Wp1[(k + 3) * HID + c0];
        fma4x4(acc, r0, r1, r2, r3, w0, w1, w2, w3);
    }
#pragma unroll
    for (int i = 0; i < 4; i++)
        *(float4*)&mid[g * 4 + i][c0] = make_float4(elu_f(acc[i][0]), elu_f(acc[i][1]),
                                                    elu_f(acc[i][2]), elu_f(acc[i][3]));
    __syncthreads();

    // 128 -> 1: 8 threads per edge, shuffle-reduce
    const int e = t >> 3, j = t & 7;
    float s = 0.f;
#pragma unroll
    for (int m = 0; m < 16; m++) {
        int cc = j * 16 + m;
        s = fmaf(mid[e][cc], Wp2[cc], s);
    }
    s += __shfl_down(s, 4, 8);
    s += __shfl_down(s, 2, 8);
    s += __shfl_down(s, 1, 8);
    if (j == 0) out[ebase + e] = s + bp2[0];
}

// ===========================================================================
extern "C" void kernel_launch(void* const* d_in, const int* in_sizes, int n_in,
                              void* d_out, int out_size, void* d_ws, size_t ws_size,
                              hipStream_t stream) {
    const float* x    = (const float*)d_in[0];
    const int*   ei   = (const int*)d_in[1];
    const float* ea   = (const float*)d_in[2];
    const float* We0  = (const float*)d_in[3];
    const float* be0  = (const float*)d_in[4];
    const float* W10  = (const float*)d_in[5];
    const float* b10  = (const float*)d_in[6];
    const float* W20  = (const float*)d_in[7];
    const float* b20  = (const float*)d_in[8];
    const float* We_s = (const float*)d_in[9];
    const float* be_s = (const float*)d_in[10];
    const float* W1_s = (const float*)d_in[11];
    const float* b1_s = (const float*)d_in[12];
    const float* W2_s = (const float*)d_in[13];
    const float* b2_s = (const float*)d_in[14];
    const float* Wp1  = (const float*)d_in[15];
    const float* bp1  = (const float*)d_in[16];
    const float* Wp2  = (const float*)d_in[17];
    const float* bp2  = (const float*)d_in[18];
    float* out = (float*)d_out;

    // workspace layout
    float* hA    = (float*)d_ws;                        // 12.8M f32
    float* hB    = hA + (size_t)N_NODES * HID;          // 12.8M f32
    float* aggr0 = hB + (size_t)N_NODES * HID;          // 1.6M f32
    int* deg     = (int*)(aggr0 + (size_t)N_NODES * NODE_IN);
    int* rowPtr  = deg + N_NODES;
    int* cursor  = rowPtr + N_NODES;
    int* edge_of = cursor + N_NODES;                    // 500k
    int* bsum    = edge_of + N_EDGES;                   // 98
    int* boff    = bsum + NB_SCAN;                      // 98

    // ----- CSR build -----
    hipMemsetAsync(deg, 0, N_NODES * sizeof(int), stream);
    deg_count_kernel<<<(N_EDGES + 255) / 256, 256, 0, stream>>>(ei, deg);
    scanA_kernel<<<NB_SCAN, SCAN_CHUNK, 0, stream>>>(deg, bsum);
    scanB_kernel<<<1, 64, 0, stream>>>(bsum, boff);
    scanC_kernel<<<NB_SCAN, SCAN_CHUNK, 0, stream>>>(deg, boff, rowPtr, cursor);
    fill_kernel<<<(N_EDGES + 255) / 256, 256, 0, stream>>>(ei, cursor, edge_of);

    // ----- layer 0 (NODE_IN -> HID) -----
    hipMemsetAsync(aggr0, 0, (size_t)N_NODES * NODE_IN * sizeof(float), stream);
    scatter0_kernel<<<(N_EDGES * NODE_IN) / 256, 256, 0, stream>>>(x, ei, ea, We0, be0, aggr0);
    mlp0_kernel<<<N_NODES / 32, 256, 0, stream>>>(x, aggr0, W10, b10, W20, b20, hA);

    // ----- layers 1..4 (HID -> HID), double-buffered -----
    float* hin = hA; float* hout = hB;
    for (int l = 0; l < 4; l++) {
        gine_fused_kernel<<<N_NODES / 32, 256, 0, stream>>>(
            hin, ei, ea, rowPtr, deg, edge_of,
            We_s + l * HID, be_s + l * HID,
            W1_s + (size_t)l * HID * HID, b1_s + l * HID,
            W2_s + (size_t)l * HID * HID, b2_s + l * HID, hout);
        float* tmp = hin; hin = hout; hout = tmp;
    }

    // ----- edge predictor -----
    pred_kernel<<<N_EDGES / 32, 256, 0, stream>>>(hin, ei, Wp1, bp1, Wp2, bp2, out);
}

// Round 3
// 1195.933 us; speedup vs baseline: 1.8673x; 1.2490x over previous
//
#include <hip/hip_runtime.h>

#define N_NODES 100000
#define N_EDGES 500000
#define NODE_IN 16
#define HID 128
#define INP 132           // padded LDS row stride (floats): 132%32=4 -> no bank aliasing
#define SCAN_CHUNK 1024
#define NB_SCAN ((N_NODES + SCAN_CHUNK - 1) / SCAN_CHUNK)   // 98

__device__ __forceinline__ float elu_f(float v) {
    return v > 0.f ? v : __expf(v) - 1.f;
}

// ===========================================================================
// CSR-by-dst build: deg -> rowPtr (3-phase scan) -> cursor -> edge_of
// ===========================================================================
__global__ void deg_count_kernel(const int* __restrict__ ei, int* __restrict__ deg) {
    int e = blockIdx.x * 256 + threadIdx.x;
    if (e < N_EDGES) atomicAdd(&deg[ei[N_EDGES + e]], 1);
}

__global__ __launch_bounds__(1024) void scanA_kernel(const int* __restrict__ deg, int* __restrict__ bsum) {
    __shared__ int s[SCAN_CHUNK];
    int i = blockIdx.x * SCAN_CHUNK + threadIdx.x;
    s[threadIdx.x] = (i < N_NODES) ? deg[i] : 0;
    __syncthreads();
    for (int off = SCAN_CHUNK / 2; off > 0; off >>= 1) {
        if (threadIdx.x < off) s[threadIdx.x] += s[threadIdx.x + off];
        __syncthreads();
    }
    if (threadIdx.x == 0) bsum[blockIdx.x] = s[0];
}

__global__ void scanB_kernel(const int* __restrict__ bsum, int* __restrict__ boff) {
    if (threadIdx.x == 0 && blockIdx.x == 0) {
        int r = 0;
        for (int i = 0; i < NB_SCAN; i++) { boff[i] = r; r += bsum[i]; }
    }
}

__global__ __launch_bounds__(1024) void scanC_kernel(const int* __restrict__ deg,
                                                     const int* __restrict__ boff,
                                                     int* __restrict__ rowPtr,
                                                     int* __restrict__ cursor) {
    __shared__ int bufA[SCAN_CHUNK], bufB[SCAN_CHUNK];
    int i = blockIdx.x * SCAN_CHUNK + threadIdx.x;
    int t = threadIdx.x;
    bufA[t] = (i < N_NODES) ? deg[i] : 0;
    __syncthreads();
    int* src = bufA; int* dst = bufB;
    for (int off = 1; off < SCAN_CHUNK; off <<= 1) {
        dst[t] = (t >= off) ? (src[t - off] + src[t]) : src[t];
        __syncthreads();
        int* tmp = src; src = dst; dst = tmp;
    }
    if (i < N_NODES) {
        int excl = (t == 0) ? 0 : src[t - 1];
        int v = excl + boff[blockIdx.x];
        rowPtr[i] = v;
        cursor[i] = v;
    }
}

__global__ void fill_kernel(const int* __restrict__ ei, int* __restrict__ cursor,
                            int* __restrict__ edge_of) {
    int e = blockIdx.x * 256 + threadIdx.x;
    if (e < N_EDGES) {
        int d = ei[N_EDGES + e];
        int p = atomicAdd(&cursor[d], 1);
        edge_of[p] = e;
    }
}

// ===========================================================================
// Layer 0 scatter (NODE_IN=16, cheap: 8M atomics)
// ===========================================================================
__global__ __launch_bounds__(256) void scatter0_kernel(
    const float* __restrict__ x, const int* __restrict__ ei,
    const float* __restrict__ ea, const float* __restrict__ We0,
    const float* __restrict__ be0, float* __restrict__ aggr)
{
    int idx = blockIdx.x * 256 + threadIdx.x;
    int e = idx >> 4, c = idx & 15;
    int s = ei[e], d = ei[N_EDGES + e];
    float m = x[s * NODE_IN + c] + ea[e] * We0[c] + be0[c];
    m = fmaxf(m, 0.f);
    atomicAdd(&aggr[d * NODE_IN + c], m);
}

// ---------------------------------------------------------------------------
// 4x4 register-blocked FMA helper: acc[i][c] += r[i][k] * w[k][c]
// ---------------------------------------------------------------------------
__device__ __forceinline__ void fma4x4(float (&acc)[4][4],
    const float4& r0, const float4& r1, const float4& r2, const float4& r3,
    const float4& w0, const float4& w1, const float4& w2, const float4& w3)
{
    float r[4][4] = {{r0.x, r0.y, r0.z, r0.w}, {r1.x, r1.y, r1.z, r1.w},
                     {r2.x, r2.y, r2.z, r2.w}, {r3.x, r3.y, r3.z, r3.w}};
    float w[4][4] = {{w0.x, w0.y, w0.z, w0.w}, {w1.x, w1.y, w1.z, w1.w},
                     {w2.x, w2.y, w2.z, w2.w}, {w3.x, w3.y, w3.z, w3.w}};
#pragma unroll
    for (int i = 0; i < 4; i++)
#pragma unroll
        for (int k = 0; k < 4; k++)
#pragma unroll
            for (int c = 0; c < 4; c++)
                acc[i][c] = fmaf(r[i][k], w[k][c], acc[i][c]);
}

// ===========================================================================
// Layer 0 MLP: h = elu( elu((x+aggr0) @ W1[16,128] + b1) @ W2[128,128] + b2 )
// ===========================================================================
__global__ __launch_bounds__(256) void mlp0_kernel(
    const float* __restrict__ x, const float* __restrict__ aggr,
    const float* __restrict__ W1, const float* __restrict__ b1,
    const float* __restrict__ W2, const float* __restrict__ b2,
    float* __restrict__ h)
{
    __shared__ float in0[32][20];
    __shared__ float mid[32][INP];
    const int t = threadIdx.x;
    const int q = t & 31, g = t >> 5;
    const int c0 = q * 4;
    const int base = blockIdx.x * 32;

    for (int i = t; i < 32 * NODE_IN; i += 256) {
        int r = i >> 4, cc = i & 15;
        int n = base + r;
        in0[r][cc] = x[n * NODE_IN + cc] + aggr[n * NODE_IN + cc];
    }
    __syncthreads();

    float4 bb = *(const float4*)&b1[c0];
    float acc[4][4];
#pragma unroll
    for (int i = 0; i < 4; i++) { acc[i][0] = bb.x; acc[i][1] = bb.y; acc[i][2] = bb.z; acc[i][3] = bb.w; }
    for (int k = 0; k < NODE_IN; k += 4) {
        float4 r0 = *(const float4*)&in0[g * 4 + 0][k];
        float4 r1 = *(const float4*)&in0[g * 4 + 1][k];
        float4 r2 = *(const float4*)&in0[g * 4 + 2][k];
        float4 r3 = *(const float4*)&in0[g * 4 + 3][k];
        float4 w0 = *(const float4*)&W1[(k + 0) * HID + c0];
        float4 w1 = *(const float4*)&W1[(k + 1) * HID + c0];
        float4 w2 = *(const float4*)&W1[(k + 2) * HID + c0];
        float4 w3 = *(const float4*)&W1[(k + 3) * HID + c0];
        fma4x4(acc, r0, r1, r2, r3, w0, w1, w2, w3);
    }
#pragma unroll
    for (int i = 0; i < 4; i++)
        *(float4*)&mid[g * 4 + i][c0] = make_float4(elu_f(acc[i][0]), elu_f(acc[i][1]),
                                                    elu_f(acc[i][2]), elu_f(acc[i][3]));
    __syncthreads();

    float4 bb2 = *(const float4*)&b2[c0];
    float acc2[4][4];
#pragma unroll
    for (int i = 0; i < 4; i++) { acc2[i][0] = bb2.x; acc2[i][1] = bb2.y; acc2[i][2] = bb2.z; acc2[i][3] = bb2.w; }
    for (int k = 0; k < HID; k += 4) {
        float4 r0 = *(const float4*)&mid[g * 4 + 0][k];
        float4 r1 = *(const float4*)&mid[g * 4 + 1][k];
        float4 r2 = *(const float4*)&mid[g * 4 + 2][k];
        float4 r3 = *(const float4*)&mid[g * 4 + 3][k];
        float4 w0 = *(const float4*)&W2[(k + 0) * HID + c0];
        float4 w1 = *(const float4*)&W2[(k + 1) * HID + c0];
        float4 w2 = *(const float4*)&W2[(k + 2) * HID + c0];
        float4 w3 = *(const float4*)&W2[(k + 3) * HID + c0];
        fma4x4(acc2, r0, r1, r2, r3, w0, w1, w2, w3);
    }
#pragma unroll
    for (int i = 0; i < 4; i++)
        *(float4*)&h[(base + g * 4 + i) * HID + c0] = make_float4(
            elu_f(acc2[i][0]), elu_f(acc2[i][1]), elu_f(acc2[i][2]), elu_f(acc2[i][3]));
}

// ===========================================================================
// Fused GINE HID layer: gather+aggregate (CSR) + Linear-ELU-Linear + outer ELU
// ===========================================================================
__global__ __launch_bounds__(256) void gine_fused_kernel(
    const float* __restrict__ hin, const int* __restrict__ ei,
    const float* __restrict__ ea, const int* __restrict__ rowPtr,
    const int* __restrict__ deg, const int* __restrict__ edge_of,
    const float* __restrict__ We, const float* __restrict__ be,
    const float* __restrict__ W1, const float* __restrict__ b1,
    const float* __restrict__ W2, const float* __restrict__ b2,
    float* __restrict__ hout)
{
    __shared__ float in[32][INP];
    __shared__ float mid[32][INP];
    const int t = threadIdx.x;
    const int q = t & 31, g = t >> 5;
    const int c0 = q * 4;
    const int base = blockIdx.x * 32;

    float4 wev = *(const float4*)&We[c0];
    float4 bev = *(const float4*)&be[c0];
#pragma unroll
    for (int i = 0; i < 4; i++) {
        int r = g * 4 + i, n = base + r;
        float4 acc = *(const float4*)&hin[n * HID + c0];
        int s0 = rowPtr[n], d = deg[n];
        for (int j = 0; j < d; j++) {
            int eid = edge_of[s0 + j];
            int s = ei[eid];
            float av = ea[eid];
            float4 hv = *(const float4*)&hin[s * HID + c0];
            acc.x += fmaxf(fmaf(av, wev.x, bev.x) + hv.x, 0.f);
            acc.y += fmaxf(fmaf(av, wev.y, bev.y) + hv.y, 0.f);
            acc.z += fmaxf(fmaf(av, wev.z, bev.z) + hv.z, 0.f);
            acc.w += fmaxf(fmaf(av, wev.w, bev.w) + hv.w, 0.f);
        }
        *(float4*)&in[r][c0] = acc;
    }
    __syncthreads();

    float4 bb = *(const float4*)&b1[c0];
    float acc[4][4];
#pragma unroll
    for (int i = 0; i < 4; i++) { acc[i][0] = bb.x; acc[i][1] = bb.y; acc[i][2] = bb.z; acc[i][3] = bb.w; }
    for (int k = 0; k < HID; k += 4) {
        float4 r0 = *(const float4*)&in[g * 4 + 0][k];
        float4 r1 = *(const float4*)&in[g * 4 + 1][k];
        float4 r2 = *(const float4*)&in[g * 4 + 2][k];
        float4 r3 = *(const float4*)&in[g * 4 + 3][k];
        float4 w0 = *(const float4*)&W1[(k + 0) * HID + c0];
        float4 w1 = *(const float4*)&W1[(k + 1) * HID + c0];
        float4 w2 = *(const float4*)&W1[(k + 2) * HID + c0];
        float4 w3 = *(const float4*)&W1[(k + 3) * HID + c0];
        fma4x4(acc, r0, r1, r2, r3, w0, w1, w2, w3);
    }
#pragma unroll
    for (int i = 0; i < 4; i++)
        *(float4*)&mid[g * 4 + i][c0] = make_float4(elu_f(acc[i][0]), elu_f(acc[i][1]),
                                                    elu_f(acc[i][2]), elu_f(acc[i][3]));
    __syncthreads();

    float4 bb2 = *(const float4*)&b2[c0];
    float acc2[4][4];
#pragma unroll
    for (int i = 0; i < 4; i++) { acc2[i][0] = bb2.x; acc2[i][1] = bb2.y; acc2[i][2] = bb2.z; acc2[i][3] = bb2.w; }
    for (int k = 0; k < HID; k += 4) {
        float4 r0 = *(const float4*)&mid[g * 4 + 0][k];
        float4 r1 = *(const float4*)&mid[g * 4 + 1][k];
        float4 r2 = *(const float4*)&mid[g * 4 + 2][k];
        float4 r3 = *(const float4*)&mid[g * 4 + 3][k];
        float4 w0 = *(const float4*)&W2[(k + 0) * HID + c0];
        float4 w1 = *(const float4*)&W2[(k + 1) * HID + c0];
        float4 w2 = *(const float4*)&W2[(k + 2) * HID + c0];
        float4 w3 = *(const float4*)&W2[(k + 3) * HID + c0];
        fma4x4(acc2, r0, r1, r2, r3, w0, w1, w2, w3);
    }
#pragma unroll
    for (int i = 0; i < 4; i++)
        *(float4*)&hout[(base + g * 4 + i) * HID + c0] = make_float4(
            elu_f(acc2[i][0]), elu_f(acc2[i][1]), elu_f(acc2[i][2]), elu_f(acc2[i][3]));
}

// ===========================================================================
// Edge predictor, factored:
//   P1 = h @ Wp1[0:128,:],  P2 = h @ Wp1[128:256,:]   (node-level, 6.6 GF)
//   out[e] = elu(P1[src]+P2[dst]+bp1) . Wp2 + bp2     (edge-level, cheap)
// ===========================================================================
__global__ __launch_bounds__(256) void pred_gemm_kernel(
    const float* __restrict__ h, const float* __restrict__ Wp1,
    float* __restrict__ P1, float* __restrict__ P2)
{
    __shared__ float in[32][INP];
    const int t = threadIdx.x;
    const int q = t & 31, g = t >> 5;
    const int c0 = q * 4;
    const int base = blockIdx.x * 32;

    for (int i = t; i < 32 * (HID / 4); i += 256) {
        int r = i >> 5, cc = (i & 31) * 4;
        *(float4*)&in[r][cc] = *(const float4*)&h[(base + r) * HID + cc];
    }
    __syncthreads();

    float acc1[4][4] = {}, acc2[4][4] = {};
    for (int k = 0; k < HID; k += 4) {
        float4 r0 = *(const float4*)&in[g * 4 + 0][k];
        float4 r1 = *(const float4*)&in[g * 4 + 1][k];
        float4 r2 = *(const float4*)&in[g * 4 + 2][k];
        float4 r3 = *(const float4*)&in[g * 4 + 3][k];
        float4 a0 = *(const float4*)&Wp1[(k + 0) * HID + c0];
        float4 a1 = *(const float4*)&Wp1[(k + 1) * HID + c0];
        float4 a2 = *(const float4*)&Wp1[(k + 2) * HID + c0];
        float4 a3 = *(const float4*)&Wp1[(k + 3) * HID + c0];
        fma4x4(acc1, r0, r1, r2, r3, a0, a1, a2, a3);
        float4 b0 = *(const float4*)&Wp1[(HID + k + 0) * HID + c0];
        float4 b1v = *(const float4*)&Wp1[(HID + k + 1) * HID + c0];
        float4 b2v = *(const float4*)&Wp1[(HID + k + 2) * HID + c0];
        float4 b3 = *(const float4*)&Wp1[(HID + k + 3) * HID + c0];
        fma4x4(acc2, r0, r1, r2, r3, b0, b1v, b2v, b3);
    }
#pragma unroll
    for (int i = 0; i < 4; i++) {
        int n = base + g * 4 + i;
        *(float4*)&P1[n * HID + c0] = make_float4(acc1[i][0], acc1[i][1], acc1[i][2], acc1[i][3]);
        *(float4*)&P2[n * HID + c0] = make_float4(acc2[i][0], acc2[i][1], acc2[i][2], acc2[i][3]);
    }
}

__global__ __launch_bounds__(256) void pred_edge_kernel(
    const float* __restrict__ P1, const float* __restrict__ P2,
    const int* __restrict__ ei, const float* __restrict__ bp1,
    const float* __restrict__ Wp2, const float* __restrict__ bp2,
    float* __restrict__ out)
{
    const int t = threadIdx.x;
    const int lane = t & 31;       // column group: 4 cols per lane
    const int eloc = t >> 5;       // 8 edges per block
    const int e = blockIdx.x * 8 + eloc;
    const int c0 = lane * 4;

    int s = ei[e], d = ei[N_EDGES + e];
    float4 a = *(const float4*)&P1[s * HID + c0];
    float4 b = *(const float4*)&P2[d * HID + c0];
    float4 bb = *(const float4*)&bp1[c0];
    float4 w = *(const float4*)&Wp2[c0];
    float r = elu_f(a.x + b.x + bb.x) * w.x
            + elu_f(a.y + b.y + bb.y) * w.y
            + elu_f(a.z + b.z + bb.z) * w.z
            + elu_f(a.w + b.w + bb.w) * w.w;
#pragma unroll
    for (int off = 16; off > 0; off >>= 1) r += __shfl_down(r, off, 32);
    if (lane == 0) out[e] = r + bp2[0];
}

// ===========================================================================
extern "C" void kernel_launch(void* const* d_in, const int* in_sizes, int n_in,
                              void* d_out, int out_size, void* d_ws, size_t ws_size,
                              hipStream_t stream) {
    const float* x    = (const float*)d_in[0];
    const int*   ei   = (const int*)d_in[1];
    const float* ea   = (const float*)d_in[2];
    const float* We0  = (const float*)d_in[3];
    const float* be0  = (const float*)d_in[4];
    const float* W10  = (const float*)d_in[5];
    const float* b10  = (const float*)d_in[6];
    const float* W20  = (const float*)d_in[7];
    const float* b20  = (const float*)d_in[8];
    const float* We_s = (const float*)d_in[9];
    const float* be_s = (const float*)d_in[10];
    const float* W1_s = (const float*)d_in[11];
    const float* b1_s = (const float*)d_in[12];
    const float* W2_s = (const float*)d_in[13];
    const float* b2_s = (const float*)d_in[14];
    const float* Wp1  = (const float*)d_in[15];
    const float* bp1  = (const float*)d_in[16];
    const float* Wp2  = (const float*)d_in[17];
    const float* bp2  = (const float*)d_in[18];
    float* out = (float*)d_out;

    // workspace layout: hA | hB | R  (R shared by {aggr0+CSR} then later P2)
    float* hA = (float*)d_ws;                          // 12.8M f32
    float* hB = hA + (size_t)N_NODES * HID;            // 12.8M f32
    float* R  = hB + (size_t)N_NODES * HID;            // 12.8M f32 region

    float* aggr0 = R;                                  // N*16 f32
    int* deg     = (int*)(aggr0 + (size_t)N_NODES * NODE_IN);
    int* rowPtr  = deg + N_NODES;
    int* cursor  = rowPtr + N_NODES;
    int* edge_of = cursor + N_NODES;                   // 500k
    int* bsum    = edge_of + N_EDGES;
    int* boff    = bsum + NB_SCAN;

    float* P1 = hB;                                    // free after layer ping-pong
    float* P2 = R;                                     // CSR dead by pred time

    // ----- CSR build -----
    hipMemsetAsync(deg, 0, N_NODES * sizeof(int), stream);
    deg_count_kernel<<<(N_EDGES + 255) / 256, 256, 0, stream>>>(ei, deg);
    scanA_kernel<<<NB_SCAN, SCAN_CHUNK, 0, stream>>>(deg, bsum);
    scanB_kernel<<<1, 64, 0, stream>>>(bsum, boff);
    scanC_kernel<<<NB_SCAN, SCAN_CHUNK, 0, stream>>>(deg, boff, rowPtr, cursor);
    fill_kernel<<<(N_EDGES + 255) / 256, 256, 0, stream>>>(ei, cursor, edge_of);

    // ----- layer 0 (NODE_IN -> HID) -----
    hipMemsetAsync(aggr0, 0, (size_t)N_NODES * NODE_IN * sizeof(float), stream);
    scatter0_kernel<<<(N_EDGES * NODE_IN) / 256, 256, 0, stream>>>(x, ei, ea, We0, be0, aggr0);
    mlp0_kernel<<<N_NODES / 32, 256, 0, stream>>>(x, aggr0, W10, b10, W20, b20, hA);

    // ----- layers 1..4 (HID -> HID), ping-pong; ends on hA -----
    float* hin = hA; float* hout = hB;
    for (int l = 0; l < 4; l++) {
        gine_fused_kernel<<<N_NODES / 32, 256, 0, stream>>>(
            hin, ei, ea, rowPtr, deg, edge_of,
            We_s + l * HID, be_s + l * HID,
            W1_s + (size_t)l * HID * HID, b1_s + l * HID,
            W2_s + (size_t)l * HID * HID, b2_s + l * HID, hout);
        float* tmp = hin; hin = hout; hout = tmp;
    }
    // hin == hA here; hB free

    // ----- edge predictor (factored) -----
    pred_gemm_kernel<<<N_NODES / 32, 256, 0, stream>>>(hin, Wp1, P1, P2);
    pred_edge_kernel<<<N_EDGES / 8, 256, 0, stream>>>(P1, P2, ei, bp1, Wp2, bp2, out);
}